// Round 14
// baseline (610.570 us; speedup 1.0000x reference)
//
#include <hip/hip_runtime.h>
#include <math.h>

#define N_PTS 131072
#define HID   256

typedef __attribute__((ext_vector_type(8)))  _Float16 f16x8;
typedef __attribute__((ext_vector_type(4)))  float    f32x4;
typedef __attribute__((ext_vector_type(16))) float    f32x16;
typedef unsigned int u32;
typedef __attribute__((address_space(1))) const u32 gu32;
typedef __attribute__((address_space(3))) u32       lu32;

// LDS map (48 KiB): act[64][512B] (32KB) | B rings: 4 waves x 2 slots x 2KB
// 48KB/block + 256 threads + (256,3) -> 3 blocks/CU (12 waves, 170-reg cap).
#define LDS_ACT 0
#define LDS_B   32768
#define LDS_SZ  49152

// act plane: rotate-swizzle within the 512B row -> b128 column reads conflict-free
__device__ __forceinline__ int act_addr(int row, int kbyte) {
    return row * 512 + ((kbyte + ((row & 31) << 4)) & 511);
}
// h = tanh(z), f1 = 1-h^2. Saturation-safe: s=inf -> h=1, f1=0.
__device__ __forceinline__ void tanh_f1(float z, float& h, float& f1) {
    float s = __expf(2.0f * z);
    float r = __builtin_amdgcn_rcpf(s + 1.0f);
    h  = fmaf(-2.0f, r, 1.0f);
    f1 = (1.0f - h) * (1.0f + h);
}

// Pre-cast W1..W3 to f16, packed as wave-private BK=16 slabs (2KB each):
// slab = (l*16 + kc)*4 + w;  w = n>>6 (column-quarter owner), kc = k>>4.
// byte = hh*1024 + j*512 + (n&31)*16 + (k&7)*2 -> B-frag b128 reads conflict-free.
// d_ws: 192 slabs x 2KB = 384KB.
__global__ void prep_w(const float* __restrict__ W1, const float* __restrict__ W2,
                       const float* __restrict__ W3, char* __restrict__ ws)
{
    int idx = blockIdx.x * 256 + threadIdx.x;     // 3*65536 elements
    int l = idx >> 16;
    int e = idx & 65535;
    int k = e >> 8, n = e & 255;
    const float* W = (l == 0) ? W1 : (l == 1) ? W2 : W3;
    float w = W[e];
    int kc = k >> 4, hh = (k >> 3) & 1, kl = k & 7;
    int wq = n >> 6, j = (n >> 5) & 1, nn = n & 31;
    size_t base = (size_t)((l * 16 + kc) * 4 + wq) * 2048;
    int byte_in = hh * 1024 + j * 512 + nn * 16 + kl * 2;
    *(_Float16*)(ws + base + byte_in) = (_Float16)w;
}

// Fused PINN forward + Taylor streams; 32x32x16 f16 MFMA, fp32 accum.
// GEMM row = S*p + s2, 64 rows/block, 4 waves; wave w owns cols [64w,64w+64).
// B WAVE-PRIVATE: BK=16 slabs, 2-slot ring, distance-1 prefetch, exact vmcnt(0)
// -> zero barriers in the K-loop. Runtime l-loop keeps regs < 170 cap (no spill).
template<int S, int PTS>
__global__ void __launch_bounds__(256, 3)
pinn_mfma(const float* __restrict__ W0, const float* __restrict__ b0,
          const float* __restrict__ b1, const float* __restrict__ b2,
          const float* __restrict__ b3,
          const float* __restrict__ W4, const float* __restrict__ b4,
          const char* __restrict__ wpre,
          const float* __restrict__ tx, float* __restrict__ out)
{
    extern __shared__ char lds[];
    const int tid  = threadIdx.x;
    const int lane = tid & 63;
    const int wid  = tid >> 6;         // 0..3: cols [64*wid, 64*wid+64)
    const int l31  = lane & 31;
    const int hh   = lane >> 5;        // k-half select
    const int h16  = hh << 4;
    const int pbase = blockIdx.x * PTS;
    constexpr int CG = 256 / PTS;
    constexpr int NC = 256 / CG;
    const int ep  = tid / CG;
    const int ec0 = (tid % CG) * NC;

    // ---------------- layer 0: 2 -> 256 (elementwise into LDS act) ----------------
    {
        const float tt = tx[2 * (pbase + ep) + 0];
        const float xx = tx[2 * (pbase + ep) + 1];
        for (int cb = ec0; cb < ec0 + NC; cb += 8) {
            alignas(16) float w0r[8], w1r[8], bb[8];
            *(f32x4*)&w0r[0] = *(const f32x4*)(W0 + cb);
            *(f32x4*)&w0r[4] = *(const f32x4*)(W0 + cb + 4);
            *(f32x4*)&w1r[0] = *(const f32x4*)(W0 + HID + cb);
            *(f32x4*)&w1r[4] = *(const f32x4*)(W0 + HID + cb + 4);
            *(f32x4*)&bb[0]  = *(const f32x4*)(b0 + cb);
            *(f32x4*)&bb[4]  = *(const f32x4*)(b0 + cb + 4);
            f16x8 vhi[S];
            #pragma unroll
            for (int j = 0; j < 8; ++j) {
                float z = fmaf(tt, w0r[j], fmaf(xx, w1r[j], bb[j]));
                float h, f1;
                tanh_f1(z, h, f1);
                vhi[0][j] = (_Float16)h;
                if (S == 2) {
                    vhi[1][j] = (_Float16)(f1 * w0r[j]);
                } else if (S == 4) {
                    float d1 = w0r[j] + w1r[j];
                    float d2 = w0r[j] - w1r[j];
                    float f2 = -2.0f * h * f1;
                    vhi[1][j] = (_Float16)(f1 * d1);
                    vhi[2][j] = (_Float16)(f1 * d2);
                    vhi[3][j] = (_Float16)(f2 * d1 * d2);
                }
            }
            #pragma unroll
            for (int s2 = 0; s2 < S; ++s2) {
                int row = ep * S + s2;      // point-interleaved
                *(f16x8*)(lds + LDS_ACT + act_addr(row, cb * 2)) = vhi[s2];
            }
        }
    }

    // bias preload: 6 scalars (selected per layer by uniform ternary — no arrays)
    const int c0 = wid * 64 + l31;
    const float b1a = b1[c0], b1b = b1[c0 + 32];
    const float b2a = b2[c0], b2b = b2[c0 + 32];
    const float b3a = b3[c0], b3b = b3[c0 + 32];

    // issue prefetch of slab 0 last (ordered after all other vmem)
    const char* srcW = wpre + (size_t)wid * 2048 + lane * 16;   // + g*8192 per slab
    char* dstW = lds + LDS_B + wid * 4096 + lane * 16;          // + (g&1)*2048
    __builtin_amdgcn_sched_barrier(0);
    __builtin_amdgcn_global_load_lds((gu32*)srcW,          (lu32*)dstW,          16, 0, 0);
    __builtin_amdgcn_global_load_lds((gu32*)(srcW + 1024), (lu32*)(dstW + 1024), 16, 0, 0);
    asm volatile("s_waitcnt lgkmcnt(0)" ::: "memory");   // act writes visible
    __builtin_amdgcn_sched_barrier(0);
    __builtin_amdgcn_s_barrier();
    __builtin_amdgcn_sched_barrier(0);

    // ---------------- layers 1..3: 256 -> 256 (runtime l-loop) ----------------
    for (int l = 0; l < 3; ++l) {
        const float biasA = (l == 0) ? b1a : (l == 1) ? b2a : b3a;
        const float biasB = (l == 0) ? b1b : (l == 1) ? b2b : b3b;
        const char* srcL = srcW + (size_t)l * 131072;    // 16 slabs x 8192

        f32x16 acc[2][2];
        #pragma unroll
        for (int i = 0; i < 2; ++i)
            #pragma unroll
            for (int j = 0; j < 2; ++j)
                acc[i][j] = (f32x16){0.f,0.f,0.f,0.f,0.f,0.f,0.f,0.f,
                                     0.f,0.f,0.f,0.f,0.f,0.f,0.f,0.f};

        #pragma unroll
        for (int ph = 0; ph < 16; ++ph) {       // BK=16 phases
            // own slab (issued 1 phase ago) is the only vmem in flight.
            // asm "memory" clobber = full fence: ds_reads can't hoist above,
            // the stage below can't sink past the next phase's wait.
            asm volatile("s_waitcnt vmcnt(0)" ::: "memory");

            const char* bslab = lds + LDS_B + wid * 4096 + (ph & 1) * 2048 + hh * 1024;
            const int kbyte = ph * 32 + h16;
            f16x8 av[2], bv[2];
            #pragma unroll
            for (int i = 0; i < 2; ++i)
                av[i] = *(const f16x8*)(lds + LDS_ACT + act_addr(i * 32 + l31, kbyte));
            #pragma unroll
            for (int j = 0; j < 2; ++j)
                bv[j] = *(const f16x8*)(bslab + j * 512 + l31 * 16);

            if (ph < 15 || l < 2) {   // stage next slab (slot (ph+1)&1)
                const char* s = srcL + (size_t)(ph + 1) * 8192;
                char* d = dstW + ((ph + 1) & 1) * 2048;
                __builtin_amdgcn_global_load_lds((gu32*)s,          (lu32*)d,          16, 0, 0);
                __builtin_amdgcn_global_load_lds((gu32*)(s + 1024), (lu32*)(d + 1024), 16, 0, 0);
            }

            __builtin_amdgcn_s_setprio(1);
            acc[0][0] = __builtin_amdgcn_mfma_f32_32x32x16_f16(av[0], bv[0], acc[0][0], 0, 0, 0);
            acc[0][1] = __builtin_amdgcn_mfma_f32_32x32x16_f16(av[0], bv[1], acc[0][1], 0, 0, 0);
            acc[1][0] = __builtin_amdgcn_mfma_f32_32x32x16_f16(av[1], bv[0], acc[1][0], 0, 0, 0);
            acc[1][1] = __builtin_amdgcn_mfma_f32_32x32x16_f16(av[1], bv[1], acc[1][1], 0, 0, 0);
            __builtin_amdgcn_s_setprio(0);
        }
        __builtin_amdgcn_s_barrier();   // all waves done READING act this layer

        // ---- in-register epilogue ----
        // C/D: col = ctile*32 + l31; row-in-tile = (reg&3)+8*(reg>>2)+4*hh
        const bool lastL = (l == 2);
        #pragma unroll
        for (int i = 0; i < 2; ++i) {
            #pragma unroll
            for (int j = 0; j < 2; ++j) {
                const int colj = wid * 64 + j * 32 + l31;
                const float bias = j ? biasB : biasA;
                const int rtb = i * 32 + 4 * hh;
                #pragma unroll
                for (int q = 0; q < 4; ++q) {
                    const int rb = rtb + 8 * q;
                    if (S == 4) {
                        float z0 = acc[i][j][4*q+0] + bias;
                        float z1 = acc[i][j][4*q+1];
                        float z2 = acc[i][j][4*q+2];
                        float zm = acc[i][j][4*q+3];
                        float h, f1;
                        tanh_f1(z0, h, f1);
                        float f2 = -2.0f * h * f1;
                        if (!lastL) {   // layer 4 reads only the mixed stream
                            *(_Float16*)(lds + LDS_ACT + act_addr(rb+0, colj*2)) = (_Float16)h;
                            *(_Float16*)(lds + LDS_ACT + act_addr(rb+1, colj*2)) = (_Float16)(f1 * z1);
                            *(_Float16*)(lds + LDS_ACT + act_addr(rb+2, colj*2)) = (_Float16)(f1 * z2);
                        }
                        *(_Float16*)(lds + LDS_ACT + act_addr(rb+3, colj*2)) =
                            (_Float16)(fmaf(f1, zm, f2 * z1 * z2));
                    } else if (S == 2) {
                        #pragma unroll
                        for (int pp = 0; pp < 2; ++pp) {
                            float z0 = acc[i][j][4*q+2*pp+0] + bias;
                            float zd = acc[i][j][4*q+2*pp+1];
                            float h, f1;
                            tanh_f1(z0, h, f1);
                            *(_Float16*)(lds + LDS_ACT + act_addr(rb+2*pp+0, colj*2)) = (_Float16)h;
                            *(_Float16*)(lds + LDS_ACT + act_addr(rb+2*pp+1, colj*2)) = (_Float16)(f1 * zd);
                        }
                    } else {
                        #pragma unroll
                        for (int m = 0; m < 4; ++m) {
                            float z0 = acc[i][j][4*q+m] + bias;
                            float h, f1;
                            tanh_f1(z0, h, f1);
                            *(_Float16*)(lds + LDS_ACT + act_addr(rb+m, colj*2)) = (_Float16)h;
                        }
                    }
                }
            }
        }
        asm volatile("s_waitcnt lgkmcnt(0)" ::: "memory");
        __builtin_amdgcn_sched_barrier(0);
        __builtin_amdgcn_s_barrier();   // new act visible
        __builtin_amdgcn_sched_barrier(0);
    }

    // ---------------- layer 4: 256 -> 1 ----------------
    if (S == 4) {
        // only the mixed stream (rows 4p+3) is needed
        const int p   = tid >> 4;     // 0..15
        const int seg = tid & 15;     // 16 lanes per point
        const int k0  = seg * 16;
        const int row = 4 * p + 3;
        float d = 0.0f;
        #pragma unroll
        for (int kb = 0; kb < 16; kb += 8) {
            f16x8 h8 = *(const f16x8*)(lds + LDS_ACT + act_addr(row, (k0 + kb) * 2));
            alignas(16) float wv[8];
            *(f32x4*)&wv[0] = *(const f32x4*)(W4 + k0 + kb);
            *(f32x4*)&wv[4] = *(const f32x4*)(W4 + k0 + kb + 4);
            #pragma unroll
            for (int j = 0; j < 8; ++j) d = fmaf((float)h8[j], wv[j], d);
        }
        #pragma unroll
        for (int off = 8; off > 0; off >>= 1) d += __shfl_down(d, off, 16);
        if (seg == 0) out[0 * N_PTS + pbase + p] = d;              // u_tt - u_xx
    } else {
        const int row = tid >> 2;     // 0..63
        const int seg = tid & 3;      // 4 lanes per row
        const int k0  = seg * 64;
        float d = 0.0f;
        #pragma unroll
        for (int kb = 0; kb < 64; kb += 8) {
            f16x8 h8 = *(const f16x8*)(lds + LDS_ACT + act_addr(row, (k0 + kb) * 2));
            alignas(16) float wv[8];
            *(f32x4*)&wv[0] = *(const f32x4*)(W4 + k0 + kb);
            *(f32x4*)&wv[4] = *(const f32x4*)(W4 + k0 + kb + 4);
            #pragma unroll
            for (int j = 0; j < 8; ++j) d = fmaf((float)h8[j], wv[j], d);
        }
        d += __shfl_down(d, 2, 4);
        d += __shfl_down(d, 1, 4);
        if (seg == 0) {
            if (S == 2) {
                const int p = row >> 1;
                if ((row & 1) == 0) out[1 * N_PTS + pbase + p] = d + b4[0];   // u_phi
                else                out[2 * N_PTS + pbase + p] = d;           // du/dt
            } else {
                out[3 * N_PTS + pbase + row] = d + b4[0];                     // u_bound
            }
        }
    }
}

extern "C" void kernel_launch(void* const* d_in, const int* in_sizes, int n_in,
                              void* d_out, int out_size, void* d_ws, size_t ws_size,
                              hipStream_t stream) {
    const float* W0 = (const float*)d_in[0];
    const float* b0 = (const float*)d_in[1];
    const float* W1 = (const float*)d_in[2];
    const float* b1 = (const float*)d_in[3];
    const float* W2 = (const float*)d_in[4];
    const float* b2 = (const float*)d_in[5];
    const float* W3 = (const float*)d_in[6];
    const float* b3 = (const float*)d_in[7];
    const float* W4 = (const float*)d_in[8];
    const float* b4 = (const float*)d_in[9];
    const float* tx_eq    = (const float*)d_in[10];
    const float* tx_init  = (const float*)d_in[11];
    const float* tx_bound = (const float*)d_in[12];
    float* out = (float*)d_out;
    char* wpre = (char*)d_ws;     // needs 384KB

    prep_w<<<768, 256, 0, stream>>>(W1, W2, W3, wpre);
    pinn_mfma<4,16><<<N_PTS/16, 256, LDS_SZ, stream>>>(W0,b0,b1,b2,b3,W4,b4,wpre,tx_eq,   out);
    pinn_mfma<2,32><<<N_PTS/32, 256, LDS_SZ, stream>>>(W0,b0,b1,b2,b3,W4,b4,wpre,tx_init, out);
    pinn_mfma<1,64><<<N_PTS/64, 256, LDS_SZ, stream>>>(W0,b0,b1,b2,b3,W4,b4,wpre,tx_bound,out);
}

// Round 15
// 578.768 us; speedup vs baseline: 1.0549x; 1.0549x over previous
//
#include <hip/hip_runtime.h>
#include <math.h>

#define N_PTS 131072
#define HID   256

typedef __attribute__((ext_vector_type(8)))  _Float16 f16x8;
typedef __attribute__((ext_vector_type(4)))  float    f32x4;
typedef __attribute__((ext_vector_type(16))) float    f32x16;
typedef unsigned int u32;
typedef __attribute__((address_space(1))) const u32 gu32;
typedef __attribute__((address_space(3))) u32       lu32;

// LDS map (48 KiB): act[64][512B] (32KB) | B rings: 8 waves x 2 slots x 1KB
// (512,4): cap 128 regs/thread, acc only 32 -> no spill; 2 blocks/CU = 16 waves.
#define LDS_ACT 0
#define LDS_B   32768
#define LDS_SZ  49152

// act plane: rotate-swizzle within the 512B row -> b128 column reads conflict-free
__device__ __forceinline__ int act_addr(int row, int kbyte) {
    return row * 512 + ((kbyte + ((row & 31) << 4)) & 511);
}
// h = tanh(z), f1 = 1-h^2. Saturation-safe: s=inf -> h=1, f1=0.
__device__ __forceinline__ void tanh_f1(float z, float& h, float& f1) {
    float s = __expf(2.0f * z);
    float r = __builtin_amdgcn_rcpf(s + 1.0f);
    h  = fmaf(-2.0f, r, 1.0f);
    f1 = (1.0f - h) * (1.0f + h);
}

// Pre-cast W1..W3 to f16, packed as wave-private BK=16 x 32-col slabs (1KB):
// slab = (l*16 + kc)*8 + wq;  wq = n>>5 (col-owner wave), kc = k>>4.
// byte = hh*512 + (n&31)*16 + (k&7)*2, hh=(k>>3)&1
// -> B-frag b128 reads are 32 consecutive n = 512B contiguous (conflict-free).
// d_ws: 384 slabs x 1KB = 384KB.
__global__ void prep_w(const float* __restrict__ W1, const float* __restrict__ W2,
                       const float* __restrict__ W3, char* __restrict__ ws)
{
    int idx = blockIdx.x * 256 + threadIdx.x;     // 3*65536 elements
    int l = idx >> 16;
    int e = idx & 65535;
    int k = e >> 8, n = e & 255;
    const float* W = (l == 0) ? W1 : (l == 1) ? W2 : W3;
    float w = W[e];
    int kc = k >> 4, hh = (k >> 3) & 1, kl = k & 7;
    int wq = n >> 5, nn = n & 31;
    size_t base = (size_t)((l * 16 + kc) * 8 + wq) * 1024;
    int byte_in = hh * 512 + nn * 16 + kl * 2;
    *(_Float16*)(ws + base + byte_in) = (_Float16)w;
}

// Fused PINN forward + Taylor streams; 32x32x16 f16 MFMA, fp32 accum.
// GEMM row = S*p + s2 (point-interleaved), 64 rows/block. 8 waves; wave w owns
// cols [32w, 32w+32) (ONE col-tile -> acc = 32 regs/thread) and both row-tiles.
// B WAVE-PRIVATE: BK=16 1KB slabs, 2-slot ring, distance-1 prefetch, exact
// vmcnt(0) -> zero barriers inside the K-loop.
template<int S, int PTS>
__global__ void __launch_bounds__(512, 4)
pinn_mfma(const float* __restrict__ W0, const float* __restrict__ b0,
          const float* __restrict__ b1, const float* __restrict__ b2,
          const float* __restrict__ b3,
          const float* __restrict__ W4, const float* __restrict__ b4,
          const char* __restrict__ wpre,
          const float* __restrict__ tx, float* __restrict__ out)
{
    extern __shared__ char lds[];
    const int tid  = threadIdx.x;
    const int lane = tid & 63;
    const int wid  = tid >> 6;         // 0..7: cols [32*wid, 32*wid+32)
    const int l31  = lane & 31;
    const int hh   = lane >> 5;        // k-half select
    const int h16  = hh << 4;
    const int pbase = blockIdx.x * PTS;
    constexpr int CG = 512 / PTS;
    constexpr int NC = 256 / CG;
    const int ep  = tid / CG;
    const int ec0 = (tid % CG) * NC;

    // ---------------- layer 0: 2 -> 256 (elementwise into LDS act) ----------------
    {
        const float tt = tx[2 * (pbase + ep) + 0];
        const float xx = tx[2 * (pbase + ep) + 1];
        for (int cb = ec0; cb < ec0 + NC; cb += 8) {
            alignas(16) float w0r[8], w1r[8], bb[8];
            *(f32x4*)&w0r[0] = *(const f32x4*)(W0 + cb);
            *(f32x4*)&w0r[4] = *(const f32x4*)(W0 + cb + 4);
            *(f32x4*)&w1r[0] = *(const f32x4*)(W0 + HID + cb);
            *(f32x4*)&w1r[4] = *(const f32x4*)(W0 + HID + cb + 4);
            *(f32x4*)&bb[0]  = *(const f32x4*)(b0 + cb);
            *(f32x4*)&bb[4]  = *(const f32x4*)(b0 + cb + 4);
            f16x8 vhi[S];
            #pragma unroll
            for (int j = 0; j < 8; ++j) {
                float z = fmaf(tt, w0r[j], fmaf(xx, w1r[j], bb[j]));
                float h, f1;
                tanh_f1(z, h, f1);
                vhi[0][j] = (_Float16)h;
                if (S == 2) {
                    vhi[1][j] = (_Float16)(f1 * w0r[j]);
                } else if (S == 4) {
                    float d1 = w0r[j] + w1r[j];
                    float d2 = w0r[j] - w1r[j];
                    float f2 = -2.0f * h * f1;
                    vhi[1][j] = (_Float16)(f1 * d1);
                    vhi[2][j] = (_Float16)(f1 * d2);
                    vhi[3][j] = (_Float16)(f2 * d1 * d2);
                }
            }
            #pragma unroll
            for (int s2 = 0; s2 < S; ++s2) {
                int row = ep * S + s2;      // point-interleaved
                *(f16x8*)(lds + LDS_ACT + act_addr(row, cb * 2)) = vhi[s2];
            }
        }
    }

    // bias preload: 3 scalars (one column per lane)
    const int c0 = wid * 32 + l31;
    const float b1a = b1[c0];
    const float b2a = b2[c0];
    const float b3a = b3[c0];

    // per-wave stage pointers: slab g lives at wpre + (g*8 + wid)*1024
    const char* srcW = wpre + (size_t)wid * 1024 + lane * 16;   // + g*8192
    char* dstW = lds + LDS_B + wid * 2048 + lane * 16;          // + (g&1)*1024

    // issue prefetch of slab 0 last (ordered after all other vmem)
    __builtin_amdgcn_sched_barrier(0);
    __builtin_amdgcn_global_load_lds((gu32*)srcW, (lu32*)dstW, 16, 0, 0);
    asm volatile("s_waitcnt lgkmcnt(0)" ::: "memory");   // act writes visible
    __builtin_amdgcn_sched_barrier(0);
    __builtin_amdgcn_s_barrier();
    __builtin_amdgcn_sched_barrier(0);

    // ---------------- layers 1..3: 256 -> 256 (runtime l-loop) ----------------
    for (int l = 0; l < 3; ++l) {
        const float bias = (l == 0) ? b1a : (l == 1) ? b2a : b3a;
        const char* srcL = srcW + (size_t)l * 131072;    // 16 slabs x 8192

        f32x16 acc0 = (f32x16){0.f,0.f,0.f,0.f,0.f,0.f,0.f,0.f,
                               0.f,0.f,0.f,0.f,0.f,0.f,0.f,0.f};
        f32x16 acc1 = acc0;

        #pragma unroll
        for (int ph = 0; ph < 16; ++ph) {       // BK=16 phases
            // own slab (issued 1 phase ago) is the only vmem in flight
            asm volatile("s_waitcnt vmcnt(0)" ::: "memory");

            const char* bslab = lds + LDS_B + wid * 2048 + (ph & 1) * 1024 + hh * 512;
            const int kbyte = ph * 32 + h16;
            f16x8 av0 = *(const f16x8*)(lds + LDS_ACT + act_addr(l31,      kbyte));
            f16x8 av1 = *(const f16x8*)(lds + LDS_ACT + act_addr(32 + l31, kbyte));
            f16x8 bv  = *(const f16x8*)(bslab + l31 * 16);

            if (ph < 15 || l < 2) {   // stage next slab (slot (ph+1)&1)
                __builtin_amdgcn_global_load_lds(
                    (gu32*)(srcL + (size_t)(ph + 1) * 8192),
                    (lu32*)(dstW + ((ph + 1) & 1) * 1024), 16, 0, 0);
            }

            __builtin_amdgcn_s_setprio(1);
            acc0 = __builtin_amdgcn_mfma_f32_32x32x16_f16(av0, bv, acc0, 0, 0, 0);
            acc1 = __builtin_amdgcn_mfma_f32_32x32x16_f16(av1, bv, acc1, 0, 0, 0);
            __builtin_amdgcn_s_setprio(0);
        }
        __builtin_amdgcn_s_barrier();   // all waves done READING act this layer

        // ---- in-register epilogue ----
        // C/D: col = wid*32 + l31; row-in-tile = (reg&3)+8*(reg>>2)+4*hh
        const bool lastL = (l == 2);
        const int colj = wid * 32 + l31;
        #pragma unroll
        for (int i = 0; i < 2; ++i) {
            const f32x16& A = i ? acc1 : acc0;
            const int rtb = i * 32 + 4 * hh;
            #pragma unroll
            for (int q = 0; q < 4; ++q) {
                const int rb = rtb + 8 * q;
                if (S == 4) {
                    float z0 = A[4*q+0] + bias;
                    float z1 = A[4*q+1];
                    float z2 = A[4*q+2];
                    float zm = A[4*q+3];
                    float h, f1;
                    tanh_f1(z0, h, f1);
                    float f2 = -2.0f * h * f1;
                    if (!lastL) {   // layer 4 reads only the mixed stream
                        *(_Float16*)(lds + LDS_ACT + act_addr(rb+0, colj*2)) = (_Float16)h;
                        *(_Float16*)(lds + LDS_ACT + act_addr(rb+1, colj*2)) = (_Float16)(f1 * z1);
                        *(_Float16*)(lds + LDS_ACT + act_addr(rb+2, colj*2)) = (_Float16)(f1 * z2);
                    }
                    *(_Float16*)(lds + LDS_ACT + act_addr(rb+3, colj*2)) =
                        (_Float16)(fmaf(f1, zm, f2 * z1 * z2));
                } else if (S == 2) {
                    #pragma unroll
                    for (int pp = 0; pp < 2; ++pp) {
                        float z0 = A[4*q+2*pp+0] + bias;
                        float zd = A[4*q+2*pp+1];
                        float h, f1;
                        tanh_f1(z0, h, f1);
                        *(_Float16*)(lds + LDS_ACT + act_addr(rb+2*pp+0, colj*2)) = (_Float16)h;
                        *(_Float16*)(lds + LDS_ACT + act_addr(rb+2*pp+1, colj*2)) = (_Float16)(f1 * zd);
                    }
                } else {
                    #pragma unroll
                    for (int m = 0; m < 4; ++m) {
                        float z0 = A[4*q+m] + bias;
                        float h, f1;
                        tanh_f1(z0, h, f1);
                        *(_Float16*)(lds + LDS_ACT + act_addr(rb+m, colj*2)) = (_Float16)h;
                    }
                }
            }
        }
        asm volatile("s_waitcnt lgkmcnt(0)" ::: "memory");
        __builtin_amdgcn_sched_barrier(0);
        __builtin_amdgcn_s_barrier();   // new act visible
        __builtin_amdgcn_sched_barrier(0);
    }

    // ---------------- layer 4: 256 -> 1 ----------------
    if (S == 4) {
        // only the mixed stream (rows 4p+3) is needed
        const int p   = tid >> 5;     // 0..15
        const int seg = tid & 31;     // 32 lanes per point
        const int k0  = seg * 8;
        const int row = 4 * p + 3;
        f16x8 h8 = *(const f16x8*)(lds + LDS_ACT + act_addr(row, k0 * 2));
        alignas(16) float wv[8];
        *(f32x4*)&wv[0] = *(const f32x4*)(W4 + k0);
        *(f32x4*)&wv[4] = *(const f32x4*)(W4 + k0 + 4);
        float d = 0.0f;
        #pragma unroll
        for (int j = 0; j < 8; ++j) d = fmaf((float)h8[j], wv[j], d);
        #pragma unroll
        for (int off = 16; off > 0; off >>= 1) d += __shfl_down(d, off, 32);
        if (seg == 0) out[0 * N_PTS + pbase + p] = d;              // u_tt - u_xx
    } else {
        const int row = tid >> 3;     // 0..63
        const int seg = tid & 7;      // 8 lanes per row
        const int k0  = seg * 32;
        float d = 0.0f;
        #pragma unroll
        for (int kb = 0; kb < 32; kb += 8) {
            f16x8 h8 = *(const f16x8*)(lds + LDS_ACT + act_addr(row, (k0 + kb) * 2));
            alignas(16) float wv[8];
            *(f32x4*)&wv[0] = *(const f32x4*)(W4 + k0 + kb);
            *(f32x4*)&wv[4] = *(const f32x4*)(W4 + k0 + kb + 4);
            #pragma unroll
            for (int j = 0; j < 8; ++j) d = fmaf((float)h8[j], wv[j], d);
        }
        d += __shfl_down(d, 4, 8);
        d += __shfl_down(d, 2, 8);
        d += __shfl_down(d, 1, 8);
        if (seg == 0) {
            if (S == 2) {
                const int p = row >> 1;
                if ((row & 1) == 0) out[1 * N_PTS + pbase + p] = d + b4[0];   // u_phi
                else                out[2 * N_PTS + pbase + p] = d;           // du/dt
            } else {
                out[3 * N_PTS + pbase + row] = d + b4[0];                     // u_bound
            }
        }
    }
}

extern "C" void kernel_launch(void* const* d_in, const int* in_sizes, int n_in,
                              void* d_out, int out_size, void* d_ws, size_t ws_size,
                              hipStream_t stream) {
    const float* W0 = (const float*)d_in[0];
    const float* b0 = (const float*)d_in[1];
    const float* W1 = (const float*)d_in[2];
    const float* b1 = (const float*)d_in[3];
    const float* W2 = (const float*)d_in[4];
    const float* b2 = (const float*)d_in[5];
    const float* W3 = (const float*)d_in[6];
    const float* b3 = (const float*)d_in[7];
    const float* W4 = (const float*)d_in[8];
    const float* b4 = (const float*)d_in[9];
    const float* tx_eq    = (const float*)d_in[10];
    const float* tx_init  = (const float*)d_in[11];
    const float* tx_bound = (const float*)d_in[12];
    float* out = (float*)d_out;
    char* wpre = (char*)d_ws;     // needs 384KB

    prep_w<<<768, 256, 0, stream>>>(W1, W2, W3, wpre);
    pinn_mfma<4,16><<<N_PTS/16, 512, LDS_SZ, stream>>>(W0,b0,b1,b2,b3,W4,b4,wpre,tx_eq,   out);
    pinn_mfma<2,32><<<N_PTS/32, 512, LDS_SZ, stream>>>(W0,b0,b1,b2,b3,W4,b4,wpre,tx_init, out);
    pinn_mfma<1,64><<<N_PTS/64, 512, LDS_SZ, stream>>>(W0,b0,b1,b2,b3,W4,b4,wpre,tx_bound,out);
}